// Round 4
// baseline (31289.203 us; speedup 1.0000x reference)
//
#include <hip/hip_runtime.h>
#include <stdint.h>

// Problem dims
#define Bn 64
#define Ln 256
#define En 256
#define Hn 512
#define Mn 256
#define HDn 64
#define On 1024
#define TOn 768
#define MP 65            // padded LDS stride of memory rows
#define NBLK 128         // persistent grid blocks (64 masters + 64 extra workers)
#define TB 1024

typedef __attribute__((ext_vector_type(2))) _Float16 h2_t;

__device__ __forceinline__ float dot2(uint32_t a, uint32_t b, float c) {
  return __builtin_amdgcn_fdot2(__builtin_bit_cast(h2_t, a),
                                __builtin_bit_cast(h2_t, b), c, false);
}
__device__ __forceinline__ uint32_t pk2(float a, float b) {
  h2_t h; h.x = (_Float16)a; h.y = (_Float16)b;
  return __builtin_bit_cast(uint32_t, h);
}
__device__ __forceinline__ float sigm(float x) {
  float e = __expf(-fabsf(x)); float s = 1.0f / (1.0f + e);
  return x >= 0.0f ? s : 1.0f - s;
}
__device__ __forceinline__ float tanh_(float x) {
  float e = __expf(-2.0f * fabsf(x)); float t = (1.0f - e) / (1.0f + e);
  return x >= 0.0f ? t : -t;
}
__device__ __forceinline__ float ln64(float v, float g, float b) {
  float s = v;
  #pragma unroll
  for (int o = 32; o; o >>= 1) s += __shfl_xor(s, o);
  float mean = s * (1.f / 64.f);
  float d = v - mean; float q = d * d;
  #pragma unroll
  for (int o = 32; o; o >>= 1) q += __shfl_xor(q, o);
  float rstd = rsqrtf(q * (1.f / 64.f) + 1e-5f);
  return d * rstd * g + b;
}
// block-wide sum & sumsq over 1024 threads (all must call)
__device__ __forceinline__ void blkstats(float v, float* red, int tid, float& S, float& Q) {
  float s = v, q = v * v;
  #pragma unroll
  for (int o = 32; o; o >>= 1) { s += __shfl_xor(s, o); q += __shfl_xor(q, o); }
  __syncthreads();
  if ((tid & 63) == 0) { red[tid >> 6] = s; red[16 + (tid >> 6)] = q; }
  __syncthreads();
  S = 0.f; Q = 0.f;
  #pragma unroll
  for (int i = 0; i < 16; i++) { S += red[i]; Q += red[16 + i]; }
}

// ---- manual grid barrier: monotonic counter, device-scope atomics ----
// Requires all NBLK blocks co-resident (1 block/CU at our LDS use; NBLK=128<=256 CUs).
// Timeout escape turns a would-be hang into a graceful wrong-answer.
__device__ __forceinline__ void gsync(unsigned* cnt, unsigned& nbar, int tid) {
  __syncthreads();
  if (tid == 0) {
    __threadfence();
    __hip_atomic_fetch_add(cnt, 1u, __ATOMIC_RELEASE, __HIP_MEMORY_SCOPE_AGENT);
    nbar++;
    const unsigned target = nbar * NBLK;
    long long t0 = clock64();
    while (__hip_atomic_load(cnt, __ATOMIC_ACQUIRE, __HIP_MEMORY_SCOPE_AGENT) < target) {
      __builtin_amdgcn_s_sleep(1);
      if (clock64() - t0 > 8000000LL) break;   // ~3ms escape hatch
    }
    __threadfence();
  }
  __syncthreads();
}

// ---------------- weight packing ----------------
// WgT[kk][row], kk<512 (k-pair index), row<2048. fp16x2 of input cols (2kk,2kk+1).
__global__ void pack_gT(const float* __restrict__ W_ih, const float* __restrict__ W_hh,
                        uint32_t* __restrict__ WgT) {
  int idx = blockIdx.x * 256 + threadIdx.x;
  if (idx >= 512 * 2048) return;
  int kk = idx >> 11, row = idx & 2047;
  float a, b;
  if (kk < 256) { int c = 2 * kk;       a = W_ih[row * 512 + c]; b = W_ih[row * 512 + c + 1]; }
  else          { int c = 2 * kk - 512; a = W_hh[row * 512 + c]; b = W_hh[row * 512 + c + 1]; }
  WgT[idx] = pk2(a, b);
}
// WhdT[kk][slot], kk<256, slot<512: [0,256)=W_rk, [256,320)=W_wk, 320=W_ws,
// [321,385)=W_er, [385,449)=W_ad, rest zero.
__global__ void pack_hT(const float* __restrict__ W_rk, const float* __restrict__ W_wk,
                        const float* __restrict__ W_ws, const float* __restrict__ W_er,
                        const float* __restrict__ W_ad, uint32_t* __restrict__ WhdT) {
  int idx = blockIdx.x * 256 + threadIdx.x;
  if (idx >= 256 * 512) return;
  int kk = idx >> 9, s = idx & 511;
  int c = 2 * kk;
  float a = 0.f, b = 0.f;
  if (s < 256)      { a = W_rk[s * 512 + c];          b = W_rk[s * 512 + c + 1]; }
  else if (s < 320) { a = W_wk[(s - 256) * 512 + c];  b = W_wk[(s - 256) * 512 + c + 1]; }
  else if (s == 320){ a = W_ws[c];                    b = W_ws[c + 1]; }
  else if (s < 385) { a = W_er[(s - 321) * 512 + c];  b = W_er[(s - 321) * 512 + c + 1]; }
  else if (s < 449) { a = W_ad[(s - 385) * 512 + c];  b = W_ad[(s - 385) * 512 + c + 1]; }
  WhdT[idx] = pk2(a, b);
}
// Wp[kk][o]: fp16x2 of W_proj row o cols (2kk,2kk+1), kk<384
__global__ void pack_proj(const float* __restrict__ W_proj, uint32_t* __restrict__ Wp) {
  int idx = blockIdx.x * blockDim.x + threadIdx.x;
  if (idx >= 1024 * 384) return;
  int o = idx / 384, kk = idx - o * 384;
  int c = 2 * kk;
  Wp[(size_t)kk * 1024 + o] = pk2(W_proj[o * 768 + c], W_proj[o * 768 + c + 1]);
}

// ---------------- persistent step kernel ----------------
struct Params {
  const float* x;
  const uint32_t *WgT, *WhdT;
  uint32_t *actT, *hnT;          // actT[512 kk][64 b], hnT[256 kk][64 b]
  float *gates, *heads;          // gates[2048 row][64 b], heads[512 slot][64 b]
  unsigned* sync;
  uint32_t* out16; float* out;
  const float *b_ih, *b_hh, *ln_in_g, *ln_in_b, *ln_h_g, *ln_h_b;
  const float *b_rk, *b_wk, *b_ws, *b_er, *b_ad;
  const float *ln_rk_g, *ln_rk_b, *ln_wk_g, *ln_wk_b, *ln_mem_g, *ln_mem_b;
  const float *ln_out_g, *ln_out_b;
};

#define SMEM_FLOATS 36256
#define SMEM_BYTES  (SMEM_FLOATS * 4)

__global__ __launch_bounds__(TB, 1) void dnc_step(Params p) {
  extern __shared__ float smem[];
  float* mem  = smem;             // 16640 (masters: memory state, padded [256][65])
  float* slab = mem + 16640;      // 8448  (all blocks: GEMM partial slabs)
  float* h32  = slab + 8448;      // 512
  float* c32  = h32 + 512;        // 512
  float* hn32 = c32 + 512;        // 512
  float* rv32 = hn32 + 512;       // 256
  float* cvec = rv32 + 256;       // 512
  float* hd   = cvec + 512;       // 512
  float* wkn  = hd + 512;         // 64
  float* rkn  = wkn + 64;         // 256
  float* erv  = rkn + 256;        // 64
  float* wvv  = erv + 64;         // 64
  float* wsc  = wvv + 64;         // 256
  float* rsc  = wsc + 256;        // 1024
  float* redA = rsc + 1024;       // 32
  float* redC = redA + 32;        // 16
  float* redD = redC + 16;        // 32
  float* misc = redD + 32;        // 16
  float* bsum = misc + 16;        // 2048
  float* bhd  = bsum + 2048;      // 512
  float* Lin_g = bhd + 512;       // 512
  float* Lin_b = Lin_g + 512;     // 512
  float* Lh_g  = Lin_b + 512;     // 512
  float* Lh_b  = Lh_g + 512;      // 512
  float* Lo_g  = Lh_b + 512;      // 768
  float* Lo_b  = Lo_g + 768;      // 768
  float* Lrk_g = Lo_b + 768;      // 64
  float* Lrk_b = Lrk_g + 64;      // 64
  float* Lwk_g = Lrk_b + 64;      // 64
  float* Lwk_b = Lwk_g + 64;      // 64
  float* Lm_g  = Lwk_b + 64;      // 64
  float* Lm_b  = Lm_g + 64;       // 64

  const int tid  = threadIdx.x;
  const int bid  = blockIdx.x;
  const int lane = tid & 63;
  const int wv   = tid >> 6;        // 0..15
  const bool master = (bid < 64);
  const int b = bid;                // batch id when master
  unsigned nbar = 0;

  // ---------------- init ----------------
  if (master) {
    for (int i = tid; i < 16640; i += TB) mem[i] = 0.f;
    if (tid < 512) {
      h32[tid] = 0.f; c32[tid] = 0.f;
      Lin_g[tid] = p.ln_in_g[tid]; Lin_b[tid] = p.ln_in_b[tid];
      Lh_g[tid]  = p.ln_h_g[tid];  Lh_b[tid]  = p.ln_h_b[tid];
      float4 bs;
      bs.x = p.b_ih[tid]        + p.b_hh[tid];
      bs.y = p.b_ih[512 + tid]  + p.b_hh[512 + tid];
      bs.z = p.b_ih[1024 + tid] + p.b_hh[1024 + tid];
      bs.w = p.b_ih[1536 + tid] + p.b_hh[1536 + tid];
      ((float4*)bsum)[tid] = bs;
      float bb = 0.f;
      if (tid < 256)       bb = p.b_rk[tid];
      else if (tid < 320)  bb = p.b_wk[tid - 256];
      else if (tid == 320) bb = p.b_ws[0];
      else if (tid < 385)  bb = p.b_er[tid - 321];
      else if (tid < 449)  bb = p.b_ad[tid - 385];
      bhd[tid] = bb;
    }
    if (tid < 768) { Lo_g[tid] = p.ln_out_g[tid]; Lo_b[tid] = p.ln_out_b[tid]; }
    if (tid < 64) {
      Lrk_g[tid] = p.ln_rk_g[tid]; Lrk_b[tid] = p.ln_rk_b[tid];
      Lwk_g[tid] = p.ln_wk_g[tid]; Lwk_b[tid] = p.ln_wk_b[tid];
      Lm_g[tid]  = p.ln_mem_g[tid]; Lm_b[tid] = p.ln_mem_b[tid];
    }
    if (tid < 256) rv32[tid] = 0.f;
    __syncthreads();
    // act for t=0: ci = LN(concat(x_0, 0)), h = 0
    if (tid < 256)      cvec[tid] = p.x[(size_t)b * 65536 + tid];
    else if (tid < 512) cvec[tid] = 0.f;
    __syncthreads();
    {
      float v = (tid < 512) ? cvec[tid] : 0.f;
      float S, Q; blkstats(v, redA, tid, S, Q);
      float mean = S * (1.f / 512.f);
      float rstd = rsqrtf(Q * (1.f / 512.f) - mean * mean + 1e-5f);
      if (tid < 256) {
        float v0 = (cvec[2 * tid]     - mean) * rstd * Lin_g[2 * tid]     + Lin_b[2 * tid];
        float v1 = (cvec[2 * tid + 1] - mean) * rstd * Lin_g[2 * tid + 1] + Lin_b[2 * tid + 1];
        p.actT[tid * 64 + b] = pk2(v0, v1);
      } else if (tid < 512) {
        p.actT[tid * 64 + b] = 0u;
      }
    }
  }
  gsync(p.sync, nbar, tid);

  // ---------------- time loop ----------------
  for (int t = 0; t < Ln; ++t) {
    // ==== S0: gates GEMM. Block owns 16 rows; wave wv owns kk [wv*32, +32). ====
    {
      const int R0 = bid * 16;
      float acc[16];
      #pragma unroll
      for (int i = 0; i < 16; i++) acc[i] = 0.f;
      const int kk0 = wv * 32;
      for (int kk = kk0; kk < kk0 + 32; ++kk) {
        uint32_t a = p.actT[kk * 64 + lane];
        const uint32_t* wr = p.WgT + (size_t)kk * 2048 + R0;
        uint4 w0 = *(const uint4*)(wr);
        uint4 w1 = *(const uint4*)(wr + 4);
        uint4 w2 = *(const uint4*)(wr + 8);
        uint4 w3 = *(const uint4*)(wr + 12);
        acc[0]  = dot2(w0.x, a, acc[0]);  acc[1]  = dot2(w0.y, a, acc[1]);
        acc[2]  = dot2(w0.z, a, acc[2]);  acc[3]  = dot2(w0.w, a, acc[3]);
        acc[4]  = dot2(w1.x, a, acc[4]);  acc[5]  = dot2(w1.y, a, acc[5]);
        acc[6]  = dot2(w1.z, a, acc[6]);  acc[7]  = dot2(w1.w, a, acc[7]);
        acc[8]  = dot2(w2.x, a, acc[8]);  acc[9]  = dot2(w2.y, a, acc[9]);
        acc[10] = dot2(w2.z, a, acc[10]); acc[11] = dot2(w2.w, a, acc[11]);
        acc[12] = dot2(w3.x, a, acc[12]); acc[13] = dot2(w3.y, a, acc[13]);
        acc[14] = dot2(w3.z, a, acc[14]); acc[15] = dot2(w3.w, a, acc[15]);
      }
      const int q = wv & 7;
      if (wv < 8) {
        #pragma unroll
        for (int r = 0; r < 16; r++) slab[q * 1056 + r * 66 + lane] = acc[r];
      }
      __syncthreads();
      if (wv >= 8) {
        #pragma unroll
        for (int r = 0; r < 16; r++) slab[q * 1056 + r * 66 + lane] += acc[r];
      }
      __syncthreads();
      {
        int r = wv, bb = lane;
        float s = 0.f;
        #pragma unroll
        for (int q2 = 0; q2 < 8; q2++) s += slab[q2 * 1056 + r * 66 + bb];
        p.gates[(size_t)(R0 + r) * 64 + bb] = s;   // [row][b] coalesced
      }
    }
    gsync(p.sync, nbar, tid);

    // ==== S1 (masters): pointwise LSTM + LN(h) -> hnT ====
    if (master) {
      if (tid < 512) {
        float4 bs = ((float4*)bsum)[tid];
        float gi = p.gates[(size_t)tid * 64 + b]          + bs.x;
        float gf = p.gates[(size_t)(512 + tid) * 64 + b]  + bs.y;
        float gg = p.gates[(size_t)(1024 + tid) * 64 + b] + bs.z;
        float go = p.gates[(size_t)(1536 + tid) * 64 + b] + bs.w;
        float c_ = sigm(gf) * c32[tid] + sigm(gi) * tanh_(gg);
        float h_ = sigm(go) * tanh_(c_);
        c32[tid] = c_; h32[tid] = h_;
      }
      __syncthreads();
      {
        float v = (tid < 512) ? h32[tid] : 0.f;
        float S, Q; blkstats(v, redA, tid, S, Q);
        float mean = S * (1.f / Hn);
        float rstd = rsqrtf(Q * (1.f / Hn) - mean * mean + 1e-5f);
        if (tid < 512) hn32[tid] = (h32[tid] - mean) * rstd * Lh_g[tid] + Lh_b[tid];
      }
      __syncthreads();
      if (tid < 256) p.hnT[tid * 64 + b] = pk2(hn32[2 * tid], hn32[2 * tid + 1]);
    }
    gsync(p.sync, nbar, tid);

    // ==== S2: heads GEMM. Block owns 4 slots; wave wv owns kk [wv*16, +16). ====
    {
      const int S0s = bid * 4;
      float a0 = 0.f, a1 = 0.f, a2 = 0.f, a3 = 0.f;
      const int kk0 = wv * 16;
      for (int kk = kk0; kk < kk0 + 16; ++kk) {
        uint32_t a = p.hnT[kk * 64 + lane];
        uint4 w = *(const uint4*)(p.WhdT + (size_t)kk * 512 + S0s);
        a0 = dot2(w.x, a, a0); a1 = dot2(w.y, a, a1);
        a2 = dot2(w.z, a, a2); a3 = dot2(w.w, a, a3);
      }
      const int q = wv & 7;
      if (wv < 8) {
        slab[q * 264 + lane]       = a0; slab[q * 264 + 66 + lane]  = a1;
        slab[q * 264 + 132 + lane] = a2; slab[q * 264 + 198 + lane] = a3;
      }
      __syncthreads();
      if (wv >= 8) {
        slab[q * 264 + lane]       += a0; slab[q * 264 + 66 + lane]  += a1;
        slab[q * 264 + 132 + lane] += a2; slab[q * 264 + 198 + lane] += a3;
      }
      __syncthreads();
      if (tid < 256) {
        int s = tid >> 6, bb = tid & 63;
        float sum = 0.f;
        #pragma unroll
        for (int q2 = 0; q2 < 8; q2++) sum += slab[q2 * 264 + s * 66 + bb];
        p.heads[(size_t)(S0s + s) * 64 + bb] = sum;   // [slot][b] coalesced
      }
    }
    gsync(p.sync, nbar, tid);

    // ==== S3 (masters): head nonlin + memory + output + next activations ====
    if (master) {
      if (tid < 512) hd[tid] = p.heads[(size_t)tid * 64 + b] + bhd[tid];
      __syncthreads();
      // P4: small LNs / nonlins (one wave each)
      {
        int wid = wv, ln = lane;
        if (wid == 0) {
          wkn[ln] = ln64(hd[256 + ln], Lwk_g[ln], Lwk_b[ln]);
        } else if (wid <= 4) {
          int n = wid - 1;
          rkn[n * 64 + ln] = ln64(hd[n * 64 + ln], Lrk_g[ln], Lrk_b[ln]);
        } else if (wid == 5) {
          erv[ln] = sigm(hd[321 + ln]);
        } else if (wid == 6) {
          wvv[ln] = tanh_(hd[385 + ln]);
        } else if (wid == 7 && ln == 0) {
          misc[0] = sigm(hd[320]);
        }
      }
      __syncthreads();
      // P5: write scores (4 threads/slot, LN(mem) on the fly)
      {
        int m = tid >> 2, q = tid & 3;
        const float* mrow = mem + m * MP + q * 16;
        float s1 = 0.f, s2 = 0.f;
        #pragma unroll
        for (int j = 0; j < 16; j++) { float v = mrow[j]; s1 += v; s2 += v * v; }
        s1 += __shfl_xor(s1, 1); s1 += __shfl_xor(s1, 2);
        s2 += __shfl_xor(s2, 1); s2 += __shfl_xor(s2, 2);
        float mean = s1 * (1.f / 64.f);
        float rstd = rsqrtf(s2 * (1.f / 64.f) - mean * mean + 1e-5f);
        float d = 0.f;
        #pragma unroll
        for (int j = 0; j < 16; j++) {
          int jj = q * 16 + j;
          float mn = (mrow[j] - mean) * rstd * Lm_g[jj] + Lm_b[jj];
          d += wkn[jj] * mn;
        }
        d += __shfl_xor(d, 1); d += __shfl_xor(d, 2);
        if (q == 0) wsc[m] = d;
      }
      __syncthreads();
      // write softmax
      float wsv = 0.f;
      if (tid < 256) {
        wsv = wsc[tid];
        float mx = wsv;
        #pragma unroll
        for (int o = 32; o; o >>= 1) mx = fmaxf(mx, __shfl_xor(mx, o));
        float e = __expf(wsv - mx);
        float sm = e;
        #pragma unroll
        for (int o = 32; o; o >>= 1) sm += __shfl_xor(sm, o);
        if ((tid & 63) == 0) { redC[tid >> 6] = mx; redC[8 + (tid >> 6)] = sm; }
      }
      __syncthreads();
      if (tid < 256) {
        float M = fmaxf(fmaxf(redC[0], redC[1]), fmaxf(redC[2], redC[3]));
        float S = redC[8]  * __expf(redC[0] - M) + redC[9]  * __expf(redC[1] - M)
                + redC[10] * __expf(redC[2] - M) + redC[11] * __expf(redC[3] - M);
        wsc[tid] = __expf(wsv - M) / S * misc[0];
      }
      __syncthreads();
      // P6+P7 fused: memory update + read scores
      {
        int m = tid >> 2, q = tid & 3;
        float w = wsc[m];
        float* mrow = mem + m * MP + q * 16;
        float vals[16];
        float s1 = 0.f, s2 = 0.f;
        #pragma unroll
        for (int j = 0; j < 16; j++) {
          int jj = q * 16 + j;
          float v = mrow[j];
          v = v * (1.f - w * erv[jj]) + w * wvv[jj];
          mrow[j] = v; vals[j] = v;
          s1 += v; s2 += v * v;
        }
        s1 += __shfl_xor(s1, 1); s1 += __shfl_xor(s1, 2);
        s2 += __shfl_xor(s2, 1); s2 += __shfl_xor(s2, 2);
        float mean = s1 * (1.f / 64.f);
        float rstd = rsqrtf(s2 * (1.f / 64.f) - mean * mean + 1e-5f);
        float d0 = 0.f, d1 = 0.f, d2 = 0.f, d3 = 0.f;
        #pragma unroll
        for (int j = 0; j < 16; j++) {
          int jj = q * 16 + j;
          float mn = (vals[j] - mean) * rstd * Lm_g[jj] + Lm_b[jj];
          d0 += rkn[jj] * mn;       d1 += rkn[64 + jj] * mn;
          d2 += rkn[128 + jj] * mn; d3 += rkn[192 + jj] * mn;
        }
        d0 += __shfl_xor(d0, 1); d0 += __shfl_xor(d0, 2);
        d1 += __shfl_xor(d1, 1); d1 += __shfl_xor(d1, 2);
        d2 += __shfl_xor(d2, 1); d2 += __shfl_xor(d2, 2);
        d3 += __shfl_xor(d3, 1); d3 += __shfl_xor(d3, 2);
        if (q == 0) { rsc[m] = d0; rsc[256 + m] = d1; rsc[512 + m] = d2; rsc[768 + m] = d3; }
      }
      __syncthreads();
      // read softmax (4 heads x 4 waves)
      float rsv;
      {
        rsv = rsc[tid];
        float mx = rsv;
        #pragma unroll
        for (int o = 32; o; o >>= 1) mx = fmaxf(mx, __shfl_xor(mx, o));
        float e = __expf(rsv - mx);
        float sm = e;
        #pragma unroll
        for (int o = 32; o; o >>= 1) sm += __shfl_xor(sm, o);
        if ((tid & 63) == 0) { redD[wv] = mx; redD[16 + wv] = sm; }
      }
      __syncthreads();
      {
        int n = tid >> 8;
        float M = fmaxf(fmaxf(redD[4 * n], redD[4 * n + 1]),
                        fmaxf(redD[4 * n + 2], redD[4 * n + 3]));
        float S = redD[16 + 4 * n]     * __expf(redD[4 * n]     - M)
                + redD[16 + 4 * n + 1] * __expf(redD[4 * n + 1] - M)
                + redD[16 + 4 * n + 2] * __expf(redD[4 * n + 2] - M)
                + redD[16 + 4 * n + 3] * __expf(redD[4 * n + 3] - M);
        rsc[tid] = __expf(rsv - M) / S;
      }
      __syncthreads();
      // P8: read_vec = rw @ memory
      {
        int out = tid >> 2, q = tid & 3;
        int n = out >> 6, j = out & 63;
        const float* rw = rsc + n * 256 + q * 64;
        float acc = 0.f;
        #pragma unroll 8
        for (int mm = 0; mm < 64; ++mm)
          acc += rw[mm] * mem[(q * 64 + mm) * MP + j];
        acc += __shfl_xor(acc, 1); acc += __shfl_xor(acc, 2);
        if (q == 0) rv32[out] = acc;
      }
      __syncthreads();
      // P9: out = LN(concat(hn, rv)) -> out16
      {
        float v = (tid < 512) ? hn32[tid] : (tid < 768 ? rv32[tid - 512] : 0.f);
        float S, Q; blkstats(v, redA, tid, S, Q);
        float mean = S * (1.f / TOn);
        float rstd = rsqrtf(Q * (1.f / TOn) - mean * mean + 1e-5f);
        if (tid < 384) {
          int e0 = 2 * tid, e1 = e0 + 1;
          float u0 = (e0 < 512) ? hn32[e0] : rv32[e0 - 512];
          float u1 = (e1 < 512) ? hn32[e1] : rv32[e1 - 512];
          u0 = (u0 - mean) * rstd * Lo_g[e0] + Lo_b[e0];
          u1 = (u1 - mean) * rstd * Lo_g[e1] + Lo_b[e1];
          p.out16[((size_t)b * Ln + t) * 384 + tid] = pk2(u0, u1);
        }
      }
      // next-step activations
      if (t < Ln - 1) {
        if (tid < 256)      cvec[tid] = p.x[((size_t)b * Ln + (t + 1)) * En + tid];
        else if (tid < 512) cvec[tid] = rv32[tid - 256];
        __syncthreads();
        float v = (tid < 512) ? cvec[tid] : 0.f;
        float S, Q; blkstats(v, redA, tid, S, Q);
        float mean = S * (1.f / 512.f);
        float rstd = rsqrtf(Q * (1.f / 512.f) - mean * mean + 1e-5f);
        if (tid < 256) {
          float v0 = (cvec[2 * tid]     - mean) * rstd * Lin_g[2 * tid]     + Lin_b[2 * tid];
          float v1 = (cvec[2 * tid + 1] - mean) * rstd * Lin_g[2 * tid + 1] + Lin_b[2 * tid + 1];
          p.actT[tid * 64 + b] = pk2(v0, v1);
        } else if (tid < 512) {
          int k = tid - 256;
          p.actT[tid * 64 + b] = pk2(h32[2 * k], h32[2 * k + 1]);
        }
      }
    }
    gsync(p.sync, nbar, tid);
  }

  // ---------------- final state outputs ----------------
  if (master) {
    const size_t OUT0 = (size_t)Bn * Ln * On;
    const size_t OUT1 = OUT0 + (size_t)Bn * Mn * HDn;
    const size_t OUT2 = OUT1 + (size_t)Bn * Hn;
    for (int i = tid; i < Mn * HDn; i += TB)
      p.out[OUT0 + (size_t)b * Mn * HDn + i] = mem[(i >> 6) * MP + (i & 63)];
    if (tid < Hn) {
      p.out[OUT1 + (size_t)b * Hn + tid] = h32[tid];
      p.out[OUT2 + (size_t)b * Hn + tid] = c32[tid];
    }
  }
}

// ---------------- deferred projection GEMM: [16384 x 768] @ [768 x 1024] ----
#define PROJ_ROWS 32
__global__ __launch_bounds__(1024, 1) void proj_gemm(const uint32_t* __restrict__ out16,
                                                     const uint32_t* __restrict__ Wp,
                                                     const float* __restrict__ b_proj,
                                                     float* __restrict__ out) {
  __shared__ uint32_t arow[PROJ_ROWS][384];
  int r0 = blockIdx.x * PROJ_ROWS;
  int tid = threadIdx.x;
  for (int i = tid; i < PROJ_ROWS * 384; i += 1024)
    ((uint32_t*)arow)[i] = out16[(size_t)r0 * 384 + i];
  __syncthreads();
  int cq = tid & 255, rg = tid >> 8;
  float acc[8][4];
  #pragma unroll
  for (int i = 0; i < 8; i++)
    #pragma unroll
    for (int j = 0; j < 4; j++) acc[i][j] = 0.f;
  for (int kk = 0; kk < 384; ++kk) {
    uint32_t w0 = Wp[(size_t)kk * 1024 + cq];
    uint32_t w1 = Wp[(size_t)kk * 1024 + cq + 256];
    uint32_t w2 = Wp[(size_t)kk * 1024 + cq + 512];
    uint32_t w3 = Wp[(size_t)kk * 1024 + cq + 768];
    #pragma unroll
    for (int i = 0; i < 8; i++) {
      uint32_t a = arow[rg * 8 + i][kk];
      acc[i][0] = dot2(w0, a, acc[i][0]); acc[i][1] = dot2(w1, a, acc[i][1]);
      acc[i][2] = dot2(w2, a, acc[i][2]); acc[i][3] = dot2(w3, a, acc[i][3]);
    }
  }
  #pragma unroll
  for (int i = 0; i < 8; i++) {
    size_t row = (size_t)r0 + rg * 8 + i;
    #pragma unroll
    for (int j = 0; j < 4; j++) {
      int c = cq + j * 256;
      out[row * 1024 + c] = acc[i][j] + b_proj[c];
    }
  }
}

// ---------------- workspace layout (bytes) ----------------
static const size_t WS_WGT   = 0;                                   // u32[512*2048] 4 MiB
static const size_t WS_WHDT  = WS_WGT   + (size_t)512 * 2048 * 4;   // u32[256*512]  512 KiB
static const size_t WS_WPJ   = WS_WHDT  + (size_t)256 * 512 * 4;    // u32[384*1024] 1.5 MiB
static const size_t WS_ACTT  = WS_WPJ   + (size_t)384 * 1024 * 4;   // u32[512*64]   128 KiB
static const size_t WS_HNT   = WS_ACTT  + (size_t)512 * 64 * 4;     // u32[256*64]   64 KiB
static const size_t WS_GATES = WS_HNT   + (size_t)256 * 64 * 4;     // f32[2048*64]  512 KiB
static const size_t WS_HEADS = WS_GATES + (size_t)2048 * 64 * 4;    // f32[512*64]   128 KiB
static const size_t WS_OUT16 = WS_HEADS + (size_t)512 * 64 * 4;     // u32[16384*384] 24 MiB
static const size_t WS_SYNC  = WS_OUT16 + (size_t)16384 * 384 * 4;  // 256 B (barrier counter)

extern "C" void kernel_launch(void* const* d_in, const int* in_sizes, int n_in,
                              void* d_out, int out_size, void* d_ws, size_t ws_size,
                              hipStream_t stream) {
  (void)in_sizes; (void)n_in; (void)out_size; (void)ws_size;
  const float* x       = (const float*)d_in[0];
  const float* W_ih    = (const float*)d_in[1];
  const float* W_hh    = (const float*)d_in[2];
  const float* b_ih    = (const float*)d_in[3];
  const float* b_hh    = (const float*)d_in[4];
  const float* ln_in_g = (const float*)d_in[5];
  const float* ln_in_b = (const float*)d_in[6];
  const float* ln_h_g  = (const float*)d_in[7];
  const float* ln_h_b  = (const float*)d_in[8];
  const float* W_rk    = (const float*)d_in[9];
  const float* b_rk    = (const float*)d_in[10];
  const float* W_wk    = (const float*)d_in[11];
  const float* b_wk    = (const float*)d_in[12];
  const float* W_ws    = (const float*)d_in[13];
  const float* b_ws    = (const float*)d_in[14];
  const float* W_er    = (const float*)d_in[15];
  const float* b_er    = (const float*)d_in[16];
  const float* W_ad    = (const float*)d_in[17];
  const float* b_ad    = (const float*)d_in[18];
  const float* ln_rk_g = (const float*)d_in[19];
  const float* ln_rk_b = (const float*)d_in[20];
  const float* ln_wk_g = (const float*)d_in[21];
  const float* ln_wk_b = (const float*)d_in[22];
  const float* ln_mem_g= (const float*)d_in[23];
  const float* ln_mem_b= (const float*)d_in[24];
  const float* ln_out_g= (const float*)d_in[25];
  const float* ln_out_b= (const float*)d_in[26];
  const float* W_proj  = (const float*)d_in[27];
  const float* b_proj  = (const float*)d_in[28];

  char* ws = (char*)d_ws;
  uint32_t* WgT   = (uint32_t*)(ws + WS_WGT);
  uint32_t* WhdT  = (uint32_t*)(ws + WS_WHDT);
  uint32_t* Wp    = (uint32_t*)(ws + WS_WPJ);
  uint32_t* actT  = (uint32_t*)(ws + WS_ACTT);
  uint32_t* hnT   = (uint32_t*)(ws + WS_HNT);
  float*    gates = (float*)(ws + WS_GATES);
  float*    heads = (float*)(ws + WS_HEADS);
  uint32_t* out16 = (uint32_t*)(ws + WS_OUT16);
  unsigned* syncp = (unsigned*)(ws + WS_SYNC);

  // zero the barrier counter (d_ws is re-poisoned to 0xAA before every replay)
  hipMemsetAsync(syncp, 0, 256, stream);

  hipLaunchKernelGGL(pack_gT, dim3(4096), dim3(256), 0, stream, W_ih, W_hh, WgT);
  hipLaunchKernelGGL(pack_hT, dim3(512), dim3(256), 0, stream,
                     W_rk, W_wk, W_ws, W_er, W_ad, WhdT);
  hipLaunchKernelGGL(pack_proj, dim3(1536), dim3(256), 0, stream, W_proj, Wp);

  Params p;
  p.x = x; p.WgT = WgT; p.WhdT = WhdT;
  p.actT = actT; p.hnT = hnT; p.gates = gates; p.heads = heads;
  p.sync = syncp; p.out16 = out16; p.out = (float*)d_out;
  p.b_ih = b_ih; p.b_hh = b_hh;
  p.ln_in_g = ln_in_g; p.ln_in_b = ln_in_b; p.ln_h_g = ln_h_g; p.ln_h_b = ln_h_b;
  p.b_rk = b_rk; p.b_wk = b_wk; p.b_ws = b_ws; p.b_er = b_er; p.b_ad = b_ad;
  p.ln_rk_g = ln_rk_g; p.ln_rk_b = ln_rk_b; p.ln_wk_g = ln_wk_g; p.ln_wk_b = ln_wk_b;
  p.ln_mem_g = ln_mem_g; p.ln_mem_b = ln_mem_b; p.ln_out_g = ln_out_g; p.ln_out_b = ln_out_b;

  hipLaunchKernelGGL(dnc_step, dim3(NBLK), dim3(TB), SMEM_BYTES, stream, p);

  hipLaunchKernelGGL(proj_gemm, dim3((Bn * Ln) / PROJ_ROWS), dim3(1024), 0, stream,
                     out16, Wp, b_proj, (float*)d_out);
}